// Round 16
// baseline (205.469 us; speedup 1.0000x reference)
//
#include <hip/hip_runtime.h>
#include <hip/hip_bf16.h>

#define B  8
#define NV 4096
#define NE 32768
#define D  128
#define KE2 384   // u-fold offset in W_edge (rows 384:512 = u part)
#define KN2 256   // u-fold offset in W_node (rows 256:384 = u part)
#define KG 384

using short8 = __attribute__((ext_vector_type(8))) short;
using f32x4  = __attribute__((ext_vector_type(4))) float;

__device__ inline unsigned short f2bf(float f) {
    unsigned u = __builtin_bit_cast(unsigned, f);
    u += 0x7FFFu + ((u >> 16) & 1u);          // RNE
    return (unsigned short)(u >> 16);
}
__device__ inline float bf2f(unsigned short h) {
    unsigned u = ((unsigned)h) << 16;
    return __builtin_bit_cast(float, u);
}
__device__ inline short8 cvt8(float4 a, float4 b) {
    union { __hip_bfloat162 h[4]; short8 v; } u;
    u.h[0] = __float22bfloat162_rn(make_float2(a.x, a.y));
    u.h[1] = __float22bfloat162_rn(make_float2(a.z, a.w));
    u.h[2] = __float22bfloat162_rn(make_float2(b.x, b.y));
    u.h[3] = __float22bfloat162_rn(make_float2(b.z, b.w));
    return u.v;
}

// ---------------------------------------------------------------------------
// weight prep (all panels n-major, K=128 each):
//  WtE1[n][k]=We[k][n]          (edges part)
//  WtP[0][n][k]=We[128+k][n]    (recv)   WtP[1][n][k]=We[256+k][n] (send)
//  WtP[2][n][k]=Wn[128+k][n]    (nodes part of node MLP)
//  WtN1[n][k]=Wn[k][n]          (e2v part)
// ---------------------------------------------------------------------------
__global__ __launch_bounds__(256) void prep_weights(
    const float* __restrict__ We, const float* __restrict__ Wn,
    unsigned short* __restrict__ WtE1, unsigned short* __restrict__ WtP,
    unsigned short* __restrict__ WtN1)
{
    const int idx   = blockIdx.x * 256 + threadIdx.x;   // 0 .. 81919
    const int which = idx >> 14;                        // 0..4
    const int r     = idx & 16383;
    const int n     = r >> 7, k = r & 127;
    if (which == 0)      WtE1[r]             = f2bf(We[(size_t)k * D + n]);
    else if (which == 1) WtP[r]              = f2bf(We[(size_t)(128 + k) * D + n]);
    else if (which == 2) WtP[16384 + r]      = f2bf(We[(size_t)(256 + k) * D + n]);
    else if (which == 3) WtP[2 * 16384 + r]  = f2bf(Wn[(size_t)(128 + k) * D + n]);
    else                 WtN1[r]             = f2bf(Wn[(size_t)k * D + n]);
}

// ---------------------------------------------------------------------------
// bias fold: bias_e[b][n] = b_e[n] + u[b]@W_e[384:,n] ; bias_n likewise
// ---------------------------------------------------------------------------
__global__ __launch_bounds__(128) void bias_kernel(
    const float* __restrict__ gu,
    const float* __restrict__ We, const float* __restrict__ be,
    const float* __restrict__ Wn, const float* __restrict__ bn,
    float* __restrict__ bias_e, float* __restrict__ bias_n)
{
    const int b = blockIdx.x, n = threadIdx.x;
    float se = be[n], sn = bn[n];
    for (int k = 0; k < D; ++k) {
        const float uk = gu[(size_t)b * D + k];
        se += uk * We[(size_t)(KE2 + k) * D + n];
        sn += uk * Wn[(size_t)(KN2 + k) * D + n];
    }
    bias_e[(size_t)b * D + n] = se;
    bias_n[(size_t)b * D + n] = sn;
}

// ---------------------------------------------------------------------------
// CSR build
// ---------------------------------------------------------------------------
__global__ __launch_bounds__(256) void hist_kernel(
    const int* __restrict__ edge_rs, const int* __restrict__ edge_masks,
    int* __restrict__ cnt)
{
    const int idx = blockIdx.x * 256 + threadIdx.x;
    if (edge_masks[idx]) {
        const int b = idx >> 15;
        const int r = edge_rs[2 * idx];
        atomicAdd(cnt + b * NV + r, 1);
    }
}

__global__ __launch_bounds__(1024) void scan_kernel(
    const int* __restrict__ cnt, int* __restrict__ off, int* __restrict__ cur)
{
    const int b = blockIdx.x, t = threadIdx.x;
    __shared__ int part[1024];
    int4 c = *(const int4*)(cnt + b * NV + t * 4);
    const int s0 = c.x, s1 = s0 + c.y, s2 = s1 + c.z, s3 = s2 + c.w;
    part[t] = s3;
    __syncthreads();
    #pragma unroll
    for (int d = 1; d < 1024; d <<= 1) {
        const int v = (t >= d) ? part[t - d] : 0;
        __syncthreads();
        part[t] += v;
        __syncthreads();
    }
    const int base = part[t] - s3;
    int* o = off + b * (NV + 1) + t * 4;
    o[0] = base; o[1] = base + s0; o[2] = base + s1; o[3] = base + s2;
    int4 cc = { base, base + s0, base + s1, base + s2 };
    *(int4*)(cur + b * NV + t * 4) = cc;
    if (t == 1023) off[b * (NV + 1) + NV] = part[1023];
}

__global__ __launch_bounds__(256) void scatter_kernel(
    const int* __restrict__ edge_rs, const int* __restrict__ edge_masks,
    int* __restrict__ cur, int* __restrict__ elist)
{
    const int idx = blockIdx.x * 256 + threadIdx.x;
    if (edge_masks[idx]) {
        const int b = idx >> 15;
        const int e = idx & (NE - 1);
        const int r = edge_rs[2 * idx];
        const int pos = atomicAdd(cur + b * NV + r, 1);
        elist[b * NE + pos] = e;
    }
}

// ---------------------------------------------------------------------------
// G2: Yp[b][v][part*128+col] = nodes[b][v] @ WtP[part]   (bf16 out, no bias)
// grid 768 = b(0..7) + (tile(0..31) + part*32)<<3. 512 thr, 128-row tile.
// ---------------------------------------------------------------------------
__global__ __launch_bounds__(512, 4) void gemm_nodes_kernel(
    const float* __restrict__ nodes,
    const unsigned short* __restrict__ WtP,
    unsigned short* __restrict__ Yp)          // (B, NV, 384) bf16
{
    __shared__ unsigned short Ash[128 * 128]; // 32 KB
    __shared__ unsigned short Wsh[128 * 128]; // 32 KB

    const int tid  = threadIdx.x;
    const int bid  = blockIdx.x;
    const int b    = bid & 7;
    const int rest = bid >> 3;
    const int tile = rest & 31;
    const int part = rest >> 5;               // 0..2
    const int n0   = tile * 128;

    const int srow = tid >> 2;
    const int sq   = tid & 3;
    const int sX   = (srow & 7) << 3;

    // stage A: nodes row (128 fp32) -> bf16 swizzled
    {
        const float* src = nodes + ((size_t)b * NV + n0 + srow) * D + sq * 32;
        #pragma unroll
        for (int j = 0; j < 4; ++j) {
            const float4 a = *(const float4*)(src + j * 8);
            const float4 c = *(const float4*)(src + j * 8 + 4);
            *(short8*)(Ash + srow * 128 + ((sq * 32 + j * 8) ^ sX)) = cvt8(a, c);
        }
        const unsigned short* ws = WtP + (size_t)part * 16384 + srow * 128 + sq * 32;
        #pragma unroll
        for (int j = 0; j < 4; ++j)
            *(short8*)(Wsh + srow * 128 + ((sq * 32 + j * 8) ^ sX)) = *(const short8*)(ws + j * 8);
    }
    __syncthreads();

    const int lane = tid & 63;
    const int wv   = tid >> 6;
    const int wr   = wv >> 2, wc = wv & 3;
    const int lc   = lane & 15, lg = lane >> 4;

    f32x4 acc[4][2] = {};
    #pragma unroll
    for (int ksub = 0; ksub < 4; ++ksub) {
        const int k = ksub * 32 + lg * 8;
        short8 afr[4], bfr[2];
        #pragma unroll
        for (int mt = 0; mt < 4; ++mt) {
            const int row = wr * 64 + mt * 16 + lc;
            afr[mt] = *(const short8*)(Ash + row * 128 + (k ^ ((row & 7) << 3)));
        }
        #pragma unroll
        for (int nt = 0; nt < 2; ++nt) {
            const int row = wc * 32 + nt * 16 + lc;
            bfr[nt] = *(const short8*)(Wsh + row * 128 + (k ^ ((row & 7) << 3)));
        }
        #pragma unroll
        for (int mt = 0; mt < 4; ++mt)
            #pragma unroll
            for (int nt = 0; nt < 2; ++nt)
                acc[mt][nt] = __builtin_amdgcn_mfma_f32_16x16x32_bf16(
                                  afr[mt], bfr[nt], acc[mt][nt], 0, 0, 0);
    }

    // epilogue: bf16 store (32B per instr across 16 lanes)
    #pragma unroll
    for (int nt = 0; nt < 2; ++nt) {
        const int col = wc * 32 + nt * 16 + lc;
        #pragma unroll
        for (int mt = 0; mt < 4; ++mt)
            #pragma unroll
            for (int r = 0; r < 4; ++r) {
                const int row = wr * 64 + mt * 16 + lg * 4 + r;
                Yp[((size_t)b * NV + n0 + row) * 384 + part * 128 + col] =
                    f2bf(acc[mt][nt][r]);
            }
    }
}

// ---------------------------------------------------------------------------
// G1 edge: edges_p = relu(edges@We1 + Y2[recv] + Y3[send] + bias_e)
// K=128 single-shot GEMM; epilogue gathers Yp rows through LDS (reused).
// grid 2048 = b + tile<<3. 512 thr = 8 waves (2x4).
// ---------------------------------------------------------------------------
__global__ __launch_bounds__(512, 4) void edge_kernel(
    const float* __restrict__ edges,
    const int*   __restrict__ edge_rs,
    const unsigned short* __restrict__ WtE1,  // (128,128) bf16 n-major
    const unsigned short* __restrict__ Yp,    // (B,NV,384) bf16
    const float* __restrict__ bias_e,
    float* __restrict__ edges_p,
    float* __restrict__ pe)                   // (B*256*2, 128) partials
{
    __shared__ unsigned short Ash[128 * 128]; // 32 KB
    __shared__ unsigned short Wsh[128 * 128]; // 32 KB

    const int tid  = threadIdx.x;
    const int bid  = blockIdx.x;
    const int b    = bid & 7;                 // XCD pin
    const int tile = bid >> 3;                // 0..255
    const int e0   = tile * 128;

    const int srow = tid >> 2;                // 0..127
    const int sq   = tid & 3;
    const int sX   = (srow & 7) << 3;

    const int2 rs = ((const int2*)edge_rs)[(size_t)b * NE + e0 + srow];

    // stage A (edges row) + W
    {
        const float* src = edges + ((size_t)b * NE + e0 + srow) * D + sq * 32;
        #pragma unroll
        for (int j = 0; j < 4; ++j) {
            const float4 a = *(const float4*)(src + j * 8);
            const float4 c = *(const float4*)(src + j * 8 + 4);
            *(short8*)(Ash + srow * 128 + ((sq * 32 + j * 8) ^ sX)) = cvt8(a, c);
        }
        const unsigned short* ws = WtE1 + srow * 128 + sq * 32;
        #pragma unroll
        for (int j = 0; j < 4; ++j)
            *(short8*)(Wsh + srow * 128 + ((sq * 32 + j * 8) ^ sX)) = *(const short8*)(ws + j * 8);
    }
    __syncthreads();

    const int lane = tid & 63;
    const int wv   = tid >> 6;
    const int wr   = wv >> 2, wc = wv & 3;
    const int lc   = lane & 15, lg = lane >> 4;

    f32x4 acc[4][2] = {};
    #pragma unroll
    for (int ksub = 0; ksub < 4; ++ksub) {
        const int k = ksub * 32 + lg * 8;
        short8 afr[4], bfr[2];
        #pragma unroll
        for (int mt = 0; mt < 4; ++mt) {
            const int row = wr * 64 + mt * 16 + lc;
            afr[mt] = *(const short8*)(Ash + row * 128 + (k ^ ((row & 7) << 3)));
        }
        #pragma unroll
        for (int nt = 0; nt < 2; ++nt) {
            const int row = wc * 32 + nt * 16 + lc;
            bfr[nt] = *(const short8*)(Wsh + row * 128 + (k ^ ((row & 7) << 3)));
        }
        #pragma unroll
        for (int mt = 0; mt < 4; ++mt)
            #pragma unroll
            for (int nt = 0; nt < 2; ++nt)
                acc[mt][nt] = __builtin_amdgcn_mfma_f32_16x16x32_bf16(
                                  afr[mt], bfr[nt], acc[mt][nt], 0, 0, 0);
    }
    __syncthreads();    // done reading Ash/Wsh

    // stage gathers: Ash <- Y2[recv[row]], Wsh <- Y3[send[row]]  (swizzled)
    {
        const unsigned short* y2 = Yp + ((size_t)b * NV + rs.x) * 384 +       sq * 32;
        const unsigned short* y3 = Yp + ((size_t)b * NV + rs.y) * 384 + 128 + sq * 32;
        #pragma unroll
        for (int j = 0; j < 4; ++j) {
            *(short8*)(Ash + srow * 128 + ((sq * 32 + j * 8) ^ sX)) = *(const short8*)(y2 + j * 8);
            *(short8*)(Wsh + srow * 128 + ((sq * 32 + j * 8) ^ sX)) = *(const short8*)(y3 + j * 8);
        }
    }
    __syncthreads();

    // epilogue: acc + Y2 + Y3 + bias, relu, store, pe partials
    #pragma unroll
    for (int nt = 0; nt < 2; ++nt) {
        const int col  = wc * 32 + nt * 16 + lc;
        const float bias = bias_e[(size_t)b * D + col];
        float csum = 0.f;
        #pragma unroll
        for (int mt = 0; mt < 4; ++mt)
            #pragma unroll
            for (int r = 0; r < 4; ++r) {
                const int row = wr * 64 + mt * 16 + lg * 4 + r;
                const int sc  = col ^ ((row & 7) << 3);
                const float y2 = bf2f(Ash[row * 128 + sc]);
                const float y3 = bf2f(Wsh[row * 128 + sc]);
                const float v = fmaxf(acc[mt][nt][r] + y2 + y3 + bias, 0.f);
                edges_p[((size_t)b * NE + e0 + row) * D + col] = v;
                csum += v;
            }
        csum += __shfl_xor(csum, 16);
        csum += __shfl_xor(csum, 32);
        if (lg == 0)
            pe[(((size_t)b * 256 + tile) * 2 + wr) * D + col] = csum;
    }
}

// ---------------------------------------------------------------------------
// Node: nodes_p = relu(e2v@Wn1 + Y4 + bias_n). 64-node tile, 256 thr = 4 waves
// (2x2: wave = 32 rows x 64 cols). A = CSR gather-sum of edges_p (K=128).
// grid 512 = b + tile<<3.
// ---------------------------------------------------------------------------
__global__ __launch_bounds__(256, 3) void node_kernel(
    const float* __restrict__ edges_p,
    const int*   __restrict__ off,
    const int*   __restrict__ elist,
    const unsigned short* __restrict__ WtN1,  // (128,128) bf16 n-major
    const unsigned short* __restrict__ Yp,    // (B,NV,384) bf16
    const float* __restrict__ bias_n,
    float* __restrict__ nodes_p,
    float* __restrict__ pn)                   // (B*64*2, 128) partials
{
    __shared__ unsigned short Ash[64 * 128];  // 16 KB
    __shared__ unsigned short Wsh[128 * 128]; // 32 KB

    const int tid  = threadIdx.x;
    const int bid  = blockIdx.x;
    const int b    = bid & 7;
    const int tile = bid >> 3;                // 0..63
    const int n0   = tile * 64;

    // A staging: 64 rows, 4 thr/row (sq quarter of 32 fp32)
    const int srow = tid >> 2;                // 0..63
    const int sq   = tid & 3;
    const int sX   = (srow & 7) << 3;
    // W staging: 128 rows, 2 thr/row
    const int srw  = tid >> 1;                // 0..127
    const int sh   = tid & 1;
    const int sXW  = (srw & 7) << 3;

    {   // e2v gather-sum -> bf16 swizzled A
        const int vtx = n0 + srow;
        const int p0  = off[b * (NV + 1) + vtx];
        const int p1  = off[b * (NV + 1) + vtx + 1];
        float4 s[8] = {};
        for (int p = p0; p < p1; ++p) {
            const int e = elist[b * NE + p];
            const float* src = edges_p + ((size_t)b * NE + e) * D + sq * 32;
            #pragma unroll
            for (int j = 0; j < 8; ++j) {
                const float4 x = *(const float4*)(src + j * 4);
                s[j].x += x.x; s[j].y += x.y; s[j].z += x.z; s[j].w += x.w;
            }
        }
        #pragma unroll
        for (int j = 0; j < 4; ++j)
            *(short8*)(Ash + srow * 128 + ((sq * 32 + j * 8) ^ sX)) =
                cvt8(s[2 * j], s[2 * j + 1]);

        const unsigned short* ws = WtN1 + srw * 128 + sh * 64;
        #pragma unroll
        for (int j = 0; j < 8; ++j)
            *(short8*)(Wsh + srw * 128 + ((sh * 64 + j * 8) ^ sXW)) = *(const short8*)(ws + j * 8);
    }
    __syncthreads();

    const int lane = tid & 63;
    const int wv   = tid >> 6;                // 0..3
    const int wr   = wv >> 1, wc = wv & 1;
    const int lc   = lane & 15, lg = lane >> 4;

    f32x4 acc[2][4] = {};
    #pragma unroll
    for (int ksub = 0; ksub < 4; ++ksub) {
        const int k = ksub * 32 + lg * 8;
        short8 afr[2], bfr[4];
        #pragma unroll
        for (int mt = 0; mt < 2; ++mt) {
            const int row = wr * 32 + mt * 16 + lc;
            afr[mt] = *(const short8*)(Ash + row * 128 + (k ^ ((row & 7) << 3)));
        }
        #pragma unroll
        for (int nt = 0; nt < 4; ++nt) {
            const int row = wc * 64 + nt * 16 + lc;
            bfr[nt] = *(const short8*)(Wsh + row * 128 + (k ^ ((row & 7) << 3)));
        }
        #pragma unroll
        for (int mt = 0; mt < 2; ++mt)
            #pragma unroll
            for (int nt = 0; nt < 4; ++nt)
                acc[mt][nt] = __builtin_amdgcn_mfma_f32_16x16x32_bf16(
                                  afr[mt], bfr[nt], acc[mt][nt], 0, 0, 0);
    }

    // epilogue: + Y4 (own row, contiguous) + bias, relu, store, pn partials
    #pragma unroll
    for (int nt = 0; nt < 4; ++nt) {
        const int col  = wc * 64 + nt * 16 + lc;
        const float bias = bias_n[(size_t)b * D + col];
        float csum = 0.f;
        #pragma unroll
        for (int mt = 0; mt < 2; ++mt)
            #pragma unroll
            for (int r = 0; r < 4; ++r) {
                const int row = wr * 32 + mt * 16 + lg * 4 + r;
                const int v   = n0 + row;
                const float y4 = bf2f(Yp[((size_t)b * NV + v) * 384 + 256 + col]);
                const float val = fmaxf(acc[mt][nt][r] + y4 + bias, 0.f);
                nodes_p[((size_t)b * NV + v) * D + col] = val;
                csum += val;
            }
        csum += __shfl_xor(csum, 16);
        csum += __shfl_xor(csum, 32);
        if (lg == 0)
            pn[(((size_t)b * 64 + tile) * 2 + wr) * D + col] = csum;
    }
}

// ---------------------------------------------------------------------------
// Partial reduce: e2u[b] = sum pe[b][0:512], v2u[b] = sum pn[b][0:128]
// ---------------------------------------------------------------------------
__global__ __launch_bounds__(256) void reduce_kernel(
    const float* __restrict__ pe, const float* __restrict__ pn,
    float* __restrict__ e2u, float* __restrict__ v2u)
{
    __shared__ float redE[2][128], redN[2][128];
    const int b = blockIdx.x;
    const int j = threadIdx.x & 127;
    const int h = threadIdx.x >> 7;
    float s = 0.f;
    for (int i = h * 256; i < h * 256 + 256; ++i)
        s += pe[((size_t)b * 512 + i) * D + j];
    float t = 0.f;
    for (int i = h * 64; i < h * 64 + 64; ++i)
        t += pn[((size_t)b * 128 + i) * D + j];
    redE[h][j] = s;
    redN[h][j] = t;
    __syncthreads();
    if (h == 0) {
        e2u[(size_t)b * D + j] = redE[0][j] + redE[1][j];
        v2u[(size_t)b * D + j] = redN[0][j] + redN[1][j];
    }
}

// ---------------------------------------------------------------------------
// Global block (fp32, tiny)
// ---------------------------------------------------------------------------
__global__ __launch_bounds__(128) void glob_kernel(
    const float* __restrict__ e2u,
    const float* __restrict__ v2u,
    const float* __restrict__ gu,
    const float* __restrict__ W_glob,
    const float* __restrict__ b_glob,
    float* __restrict__ glob_p)
{
    __shared__ float gin[KG];
    const int b = blockIdx.x;
    const int j = threadIdx.x;

    gin[j      ] = e2u[(size_t)b * D + j];
    gin[j + 128] = v2u[(size_t)b * D + j];
    gin[j + 256] = gu [(size_t)b * D + j];
    __syncthreads();

    float acc = b_glob[j];
    #pragma unroll 4
    for (int k = 0; k < KG; ++k)
        acc += gin[k] * W_glob[(size_t)k * D + j];
    glob_p[(size_t)b * D + j] = fmaxf(acc, 0.f);
}

// ---------------------------------------------------------------------------
extern "C" void kernel_launch(void* const* d_in, const int* in_sizes, int n_in,
                              void* d_out, int out_size, void* d_ws, size_t ws_size,
                              hipStream_t stream) {
    const float* nodes      = (const float*)d_in[0];
    const float* edges      = (const float*)d_in[1];
    const float* gu         = (const float*)d_in[2];
    const int*   edge_rs    = (const int*)d_in[3];
    const int*   edge_masks = (const int*)d_in[4];
    const float* W_edge     = (const float*)d_in[5];
    const float* b_edge     = (const float*)d_in[6];
    const float* W_node     = (const float*)d_in[7];
    const float* b_node     = (const float*)d_in[8];
    const float* W_glob     = (const float*)d_in[9];
    const float* b_glob     = (const float*)d_in[10];

    float* out     = (float*)d_out;
    float* nodes_p = out;
    float* edges_p = out + (size_t)B * NV * D;
    float* glob_p  = edges_p + (size_t)B * NE * D;

    // workspace layout
    int*   cnt    = (int*)d_ws;                        // B*NV
    int*   off    = cnt + (size_t)B * NV;              // B*(NV+1)
    int*   cur    = off + (size_t)B * (NV + 1);        // B*NV
    int*   elist  = cur + (size_t)B * NV;              // B*NE
    float* e2u    = (float*)(elist + (size_t)B * NE);  // B*D
    float* v2u    = e2u + (size_t)B * D;               // B*D
    float* bias_e = v2u + (size_t)B * D;               // B*D
    float* bias_n = bias_e + (size_t)B * D;            // B*D
    float* pe     = bias_n + (size_t)B * D;            // B*512*D
    float* pn     = pe + (size_t)B * 512 * D;          // B*128*D
    unsigned short* Yp   = (unsigned short*)(pn + (size_t)B * 128 * D); // B*NV*384
    unsigned short* WtE1 = Yp + (size_t)B * NV * 384;  // 16384
    unsigned short* WtP  = WtE1 + 16384;               // 3*16384
    unsigned short* WtN1 = WtP + 3 * 16384;            // 16384

    hipMemsetAsync(cnt, 0, (size_t)B * NV * sizeof(int), stream);

    prep_weights<<<(5 * 16384) / 256, 256, 0, stream>>>(W_edge, W_node, WtE1, WtP, WtN1);
    bias_kernel<<<B, 128, 0, stream>>>(gu, W_edge, b_edge, W_node, b_node, bias_e, bias_n);
    hist_kernel<<<(B * NE) / 256, 256, 0, stream>>>(edge_rs, edge_masks, cnt);
    scan_kernel<<<B, 1024, 0, stream>>>(cnt, off, cur);
    scatter_kernel<<<(B * NE) / 256, 256, 0, stream>>>(edge_rs, edge_masks, cur, elist);

    // projections of node features (Y2|Y3|Y4), bf16, L2-pinned per batch
    gemm_nodes_kernel<<<3 * 32 * B, 512, 0, stream>>>(nodes, WtP, Yp);
    // edge MLP with gathered projections
    edge_kernel<<<(NE / 128) * B, 512, 0, stream>>>(edges, edge_rs, WtE1, Yp,
                                                    bias_e, edges_p, pe);
    // node MLP with CSR-gathered e2v
    node_kernel<<<(NV / 64) * B, 256, 0, stream>>>(edges_p, off, elist, WtN1, Yp,
                                                   bias_n, nodes_p, pn);
    reduce_kernel<<<B, 256, 0, stream>>>(pe, pn, e2u, v2u);
    glob_kernel<<<B, 128, 0, stream>>>(e2u, v2u, gu, W_glob, b_glob, glob_p);
}